// Round 9
// baseline (298.708 us; speedup 1.0000x reference)
//
#include <hip/hip_runtime.h>

#define NN 4096
#define FF 128
#define EE 64

typedef unsigned short u16;
typedef unsigned long long u64;

__device__ __forceinline__ float lrelu(float x) { return x > 0.f ? x : 0.2f * x; }

// K0: v6[vi][f] = sum_e W_d[f,e] * a_d[e]   (vi = 2*d + {0:a1, 1:a2})
__global__ void k_prep(const float* __restrict__ Wf, const float* __restrict__ af1, const float* __restrict__ af2,
                       const float* __restrict__ Wb, const float* __restrict__ ab1, const float* __restrict__ ab2,
                       const float* __restrict__ Wg, const float* __restrict__ ag1, const float* __restrict__ ag2,
                       float* __restrict__ v6)
{
    const float* Ws[3]  = {Wf, Wb, Wg};
    const float* a1s[3] = {af1, ab1, ag1};
    const float* a2s[3] = {af2, ab2, ag2};
    int tid = threadIdx.x;
    for (int idx = tid; idx < 6 * FF; idx += 256) {
        int vi = idx >> 7, f = idx & (FF - 1), dd = vi >> 1;
        const float* a = (vi & 1) ? a2s[dd] : a1s[dd];
        const float* W = Ws[dd];
        float s = 0.f;
        for (int e = 0; e < EE; ++e) s += W[(size_t)f * EE + e] * a[e];
        v6[idx] = s;
    }
}

// K1: per node n: u[n,:] = t[n,:]@weight.T ; out rows 0..63 = u.T ; s1_d[n], p_d[n].
// Blocks 0..15 also zero the CSC column counters.
__global__ void k_feat(const float* __restrict__ t, const float* __restrict__ weight,
                       const float* __restrict__ v6,
                       float* __restrict__ u, float* __restrict__ s1, float* __restrict__ p,
                       float* __restrict__ out, int* __restrict__ ccnt)
{
    __shared__ __attribute__((aligned(16))) float tt[FF];
    __shared__ float vv[6 * FF];
    int n = blockIdx.x, tid = threadIdx.x;
    if (n < 16) ccnt[n * 256 + tid] = 0;
    if (tid < FF) tt[tid] = t[(size_t)n * FF + tid];
    for (int idx = tid; idx < 6 * FF; idx += 256) vv[idx] = v6[idx];
    __syncthreads();
    int e = tid >> 2, part = tid & 3;
    const float4* w4 = reinterpret_cast<const float4*>(weight + (size_t)e * FF + part * 32);
    const float4* t4 = reinterpret_cast<const float4*>(tt + part * 32);
    float s = 0.f;
    #pragma unroll
    for (int q8 = 0; q8 < 8; ++q8) {
        float4 w = w4[q8]; float4 x = t4[q8];
        s += w.x * x.x + w.y * x.y + w.z * x.z + w.w * x.w;
    }
    s += __shfl_xor(s, 1); s += __shfl_xor(s, 2);
    if (part == 0) {
        u[(size_t)n * EE + e] = s;
        out[(size_t)e * NN + n] = s;
    }
    if (tid < 64) {
        float t0 = tt[tid], t1 = tt[64 + tid];
        for (int vi = 0; vi < 6; ++vi) {
            float x = t0 * vv[vi * FF + tid] + t1 * vv[vi * FF + 64 + tid];
            for (int off = 32; off; off >>= 1) x += __shfl_xor(x, off);
            if (tid == 0) {
                int dd = vi >> 1;
                if (vi & 1) p[dd * NN + n] = x; else s1[dd * NN + n] = x;
            }
        }
    }
}

// K2a: PURE streaming pass. One wave per row: 16 coalesced float4 loads,
// 4 ballots each -> 4096-bit presence mask (64 u64 words/row). No scan, no
// divergence, no dependent loads — waves return to streaming immediately.
// Bit convention: word w = j*4+c (j=load idx, c=component) covers columns
// j*256 + L*4 + c at bit L (L = lane).
__global__ void k_mask(const float* __restrict__ Af, const float* __restrict__ Ab, const float* __restrict__ Ag,
                       u64* __restrict__ masks)
{
    int wid = threadIdx.x >> 6, lane = threadIdx.x & 63;
    int gr = blockIdx.x * 4 + wid;             // 0 .. 3*NN-1
    int d = gr >> 12, r = gr & (NN - 1);
    const float* A = d == 0 ? Af : (d == 1 ? Ab : Ag);
    const float4* row4 = reinterpret_cast<const float4*>(A + (size_t)r * NN);
    u64 w = 0ull;
    #pragma unroll
    for (int j = 0; j < 16; ++j) {
        float4 L = row4[j * 64 + lane];
        u64 bx = __ballot(L.x != 0.f);
        u64 by = __ballot(L.y != 0.f);
        u64 bz = __ballot(L.z != 0.f);
        u64 bw = __ballot(L.w != 0.f);
        int base = j * 4;
        if (lane == base)     w = bx;
        if (lane == base + 1) w = by;
        if (lane == base + 2) w = bz;
        if (lane == base + 3) w = bw;
    }
    masks[(size_t)gr * 64 + lane] = w;
}

// K2b: mask -> CSR (+ CSC, q, s2). One wave per row, reads 512 B of mask.
__global__ void k_csr(const u64* __restrict__ masks, const float* __restrict__ p,
                      u16* __restrict__ csr, int* __restrict__ cnt, float* __restrict__ s2,
                      u16* __restrict__ csc, int* __restrict__ ccnt, int stride)
{
    int wid = threadIdx.x >> 6, lane = threadIdx.x & 63;
    int gr = blockIdx.x * 4 + wid;
    int d = gr >> 12, r = gr & (NN - 1);
    u64 m = masks[(size_t)gr * 64 + lane];
    int lc = __popcll(m);
    int sc = lc;
    for (int off = 1; off < 64; off <<= 1) {
        int o = __shfl_up(sc, off);
        if (lane >= off) sc += o;
    }
    int total = __shfl(sc, 63);
    int pos = sc - lc;                          // exclusive offset
    const float* pd = p + d * NN;
    u16* crow = csr + (size_t)gr * stride;
    int colbase = (lane >> 2) * 256 + (lane & 3);
    float q = 0.f;
    while (m) {
        int b = __ffsll(m) - 1;
        m &= m - 1;
        int col = colbase + b * 4;
        if (pos < stride) crow[pos] = (u16)col;
        pos++;
        q += pd[col];
        if (d == 1) {
            int cp = atomicAdd(&ccnt[col], 1);
            if (cp < stride) csc[(size_t)col * stride + cp] = (u16)r;
        }
    }
    for (int off = 32; off; off >>= 1) q += __shfl_xor(q, off);
    if (lane == 0) {
        cnt[gr] = total;
        s2[gr] = q / fmaxf((float)total, 1.f);
    }
}

// K3: backward row denominators Zb[j] = sum_{col} exp(lrelu(s1b[j]+s2b[col]))
__global__ void k_zb(const float* __restrict__ s1, const float* __restrict__ s2,
                     const u16* __restrict__ csr, const int* __restrict__ cnt, int stride,
                     float* __restrict__ Zb)
{
    int tid = threadIdx.x, wave = tid >> 6, lane = tid & 63;
    int j = blockIdx.x * 4 + wave;
    int gr = NN + j;
    int nnz = min(cnt[gr], stride);
    const u16* crow = csr + (size_t)gr * stride;
    float s1j = s1[gr];
    const float* s2b = s2 + NN;
    float z = 0.f;
    if (lane < nnz)      z += __expf(lrelu(s1j + s2b[crow[lane]]));
    if (lane + 64 < nnz) z += __expf(lrelu(s1j + s2b[crow[lane + 64]]));
    for (int off = 32; off; off >>= 1) z += __shfl_xor(z, off);
    if (lane == 0) Zb[j] = z;
}

// K4: unified consumer, one block per (d, i):
//  d==0: fwd row-softmax gather (CSR)  -> out rows  64..127
//  d==1: bwd column gather     (CSC)   -> out rows 128..191
//  d==2: geo row-softmax gather (CSR)  -> out rows 192..255
__global__ void k_out(const float* __restrict__ u,
                      const float* __restrict__ s1, const float* __restrict__ s2,
                      const float* __restrict__ Zb,
                      const u16* __restrict__ csr, const int* __restrict__ cnt,
                      const u16* __restrict__ csc, const int* __restrict__ ccnt, int stride,
                      float* __restrict__ out)
{
    __shared__ float wl[128]; __shared__ int il[128];
    __shared__ float zsum; __shared__ float oacc[4 * EE];
    int gr = blockIdx.x;
    int d = gr >> 12, i = gr & (NN - 1);
    int tid = threadIdx.x, wave = tid >> 6, lane = tid & 63;
    if (tid == 0) zsum = 0.f;
    __syncthreads();
    float invz;
    int nnz;
    if (d == 1) {
        nnz = min(ccnt[i], stride);
        const u16* ccol = csc + (size_t)i * stride;
        float s2i = s2[NN + i];
        if (tid < nnz) {
            int j = ccol[tid];
            il[tid] = j;
            wl[tid] = __expf(lrelu(s1[NN + j] + s2i)) / Zb[j];
        }
        invz = 1.f;
        __syncthreads();
    } else {
        nnz = min(cnt[gr], stride);
        const u16* crow = csr + (size_t)gr * stride;
        float s1i = s1[gr];
        const float* s2d = s2 + d * NN;
        float z = 0.f;
        if (tid < nnz) {
            int col = crow[tid];
            float w = __expf(lrelu(s1i + s2d[col]));
            il[tid] = col; wl[tid] = w; z = w;
        }
        for (int off = 32; off; off >>= 1) z += __shfl_xor(z, off);
        if (lane == 0) atomicAdd(&zsum, z);
        __syncthreads();
        float zs = zsum;
        invz = zs > 0.f ? 1.f / zs : 0.f;
    }
    float a0 = 0.f, a1 = 0.f;
    int k = wave;
    for (; k + 4 < nnz; k += 8) {
        a0 += wl[k]     * u[(size_t)il[k]     * EE + lane];
        a1 += wl[k + 4] * u[(size_t)il[k + 4] * EE + lane];
    }
    for (; k < nnz; k += 4)
        a0 += wl[k] * u[(size_t)il[k] * EE + lane];
    oacc[wave * EE + lane] = a0 + a1;
    __syncthreads();
    if (wave == 0) {
        float rsum = (oacc[lane] + oacc[EE + lane] + oacc[2 * EE + lane] + oacc[3 * EE + lane]) * invz;
        int base = 64 + (d << 6);   // d0->64 (fwd), d1->128 (bwd), d2->192 (geo)
        out[(size_t)(base + lane) * NN + i] = rsum;
    }
}

extern "C" void kernel_launch(void* const* d_in, const int* in_sizes, int n_in,
                              void* d_out, int out_size, void* d_ws, size_t ws_size,
                              hipStream_t stream)
{
    const float* t   = (const float*)d_in[0];
    const float* Ag  = (const float*)d_in[1];
    const float* Af  = (const float*)d_in[2];
    const float* Ab  = (const float*)d_in[3];
    const float* W   = (const float*)d_in[4];
    const float* Wf  = (const float*)d_in[5];
    const float* af1 = (const float*)d_in[6];
    const float* af2 = (const float*)d_in[7];
    const float* Wb  = (const float*)d_in[8];
    const float* ab1 = (const float*)d_in[9];
    const float* ab2 = (const float*)d_in[10];
    const float* Wg  = (const float*)d_in[11];
    const float* ag1 = (const float*)d_in[12];
    const float* ag2 = (const float*)d_in[13];
    float* out = (float*)d_out;

    char* wsb = (char*)d_ws;
    u64*   masks = (u64*)wsb;                       // 3N*64 u64 = 6 MB (16B-aligned base)
    float* v6  = (float*)(wsb + (size_t)3 * NN * 64 * 8);  // 768
    float* s1  = v6 + 6 * FF;                       // 3N
    float* p   = s1 + 3 * NN;                       // 3N
    float* s2  = p + 3 * NN;                        // 3N
    float* Zb  = s2 + 3 * NN;                       // N
    float* u   = Zb + NN;                           // N*E
    int*   cnt  = (int*)(u + (size_t)NN * EE);      // 3N
    int*   ccnt = cnt + 3 * NN;                     // N
    u16*   csr  = (u16*)(ccnt + NN);                // 3N*stride
    // csc follows csr: N*stride

    size_t base_bytes = ((char*)csr) - wsb;
    int stride = 128;
    if (base_bytes + (size_t)4 * NN * 128 * 2 > ws_size) stride = 96;
    if (base_bytes + (size_t)4 * NN * 96 * 2 > ws_size)  stride = 64;
    u16* csc = csr + (size_t)3 * NN * stride;

    k_prep<<<1, 256, 0, stream>>>(Wf, af1, af2, Wb, ab1, ab2, Wg, ag1, ag2, v6);
    k_feat<<<NN, 256, 0, stream>>>(t, W, v6, u, s1, p, out, ccnt);
    k_mask<<<3 * NN / 4, 256, 0, stream>>>(Af, Ab, Ag, masks);
    k_csr<<<3 * NN / 4, 256, 0, stream>>>(masks, p, csr, cnt, s2, csc, ccnt, stride);
    k_zb<<<NN / 4, 256, 0, stream>>>(s1, s2, csr, cnt, stride, Zb);
    k_out<<<3 * NN, 256, 0, stream>>>(u, s1, s2, Zb, csr, cnt, csc, ccnt, stride, out);
}